// Round 1
// baseline (901.284 us; speedup 1.0000x reference)
//
#include <hip/hip_runtime.h>

#define HH 512
#define WW 512
#define MBS 8
#define PPP 8
#define TT 16
#define NF 14   // pred/target frames per video
#define NV 4    // videos
#define CRP 17
#define CW 478  // cropped width
#define TGT_SIZE ((size_t)NV * NF * CW * CW)

__device__ __forceinline__ double wave_sum64(double v) {
    #pragma unroll
    for (int off = 1; off < 64; off <<= 1)
        v += __shfl_xor(v, off, 64);
    return v;
}

// Wave-cooperative SAD cost (exact sum of f32 abs-diffs, accumulated in f64).
// Returns sum (= 64 * mean); relative order identical to reference means.
__device__ __forceinline__ double cost_sum(const float* __restrict__ imgI,
                                           int i, int j, int y, int x,
                                           float p, int r, int c) {
    bool valid = (y >= 0) & (y + MBS <= HH) & (x >= 0) & (x + MBS <= WW)
               & (y - i <= PPP) & (i - y <= PPP) & (x - j <= PPP) & (j - x <= PPP);
    if (!valid) return 1e30;  // LARGE sentinel (wave-uniform branch)
    float rv = imgI[(y + r) * WW + (x + c)];
    double d = (double)fabsf(p - rv);
    return wave_sum64(d);
}

__global__ void __launch_bounds__(256)
motion_pred_kernel(const float* __restrict__ x, float* __restrict__ out) {
    int wave = (int)((blockIdx.x * blockDim.x + threadIdx.x) >> 6);
    int lane = threadIdx.x & 63;

    int bj  = wave & 63;          // block col
    int bi  = (wave >> 6) & 63;   // block row
    int bf  = wave >> 12;         // 0 .. NV*NF-1
    int f   = bf % NF;
    int b   = bf / NF;

    const float* imgP = x + (size_t)(b * TT + f + 1) * HH * WW;  // current (warp source)
    const float* imgI = x + (size_t)(b * TT + f)     * HH * WW;  // reference

    int i = bi * MBS, j = bj * MBS;
    int r = lane >> 3, c = lane & 7;
    float p = imgP[(i + r) * WW + (j + c)];  // this lane's block pixel

    // LDSP/SDSP tables as (dx, dy) — matches reference d[0]=dx, d[1]=dy
    const int LDx[9] = {0,-1, 1,-2, 0, 2,-1, 1, 0};
    const int LDy[9] = {-2,-1,-1, 0, 0, 0, 1, 1, 2};
    const int SDx[5] = {0,-1, 0, 1, 0};
    const int SDy[5] = {-1, 0, 0, 0, 1};

    double c0 = cost_sum(imgI, i, j, i, j, p, r, c);
    int pt = (c0 == 0.0) ? 4 : -1;
    int y = i, xx = j, k = 0;

    while (pt != 4 && k < 16) {
        double best = 1e300;
        int bidx = 0;
        #pragma unroll
        for (int q = 0; q < 9; ++q) {
            double cs = cost_sum(imgI, i, j, y + LDy[q], xx + LDx[q], p, r, c);
            if (cs < best) { best = cs; bidx = q; }   // strict '<' => first-min (jnp.argmin)
        }
        pt = bidx;
        y  += LDy[pt];
        xx += LDx[pt];
        k++;
    }

    // SDSP refinement
    {
        double best = 1e300;
        int bidx = 0;
        #pragma unroll
        for (int q = 0; q < 5; ++q) {
            double cs = cost_sum(imgI, i, j, y + SDy[q], xx + SDx[q], p, r, c);
            if (cs < best) { best = cs; bidx = q; }
        }
        y  += SDy[bidx];
        xx += SDx[bidx];
    }

    int dy = y - i, dx = xx - j;

    // write this lane's warped pixel (pred), cropped
    int gy = i + r, gx = j + c;
    if (gy >= CRP && gy < HH - CRP && gx >= CRP && gx < WW - CRP) {
        float v = imgP[(i + dy + r) * WW + (j + dx + c)];
        size_t oidx = TGT_SIZE +
            ((((size_t)b * NF + f) * CW + (size_t)(gy - CRP)) * CW + (size_t)(gx - CRP));
        out[oidx] = v;
    }
}

__global__ void __launch_bounds__(256)
target_copy_kernel(const float* __restrict__ x, float* __restrict__ out) {
    size_t idx = (size_t)blockIdx.x * blockDim.x + threadIdx.x;
    if (idx >= TGT_SIZE) return;
    int xcol = (int)(idx % CW);
    size_t t1 = idx / CW;
    int yrow = (int)(t1 % CW);
    size_t t2 = t1 / CW;
    int f = (int)(t2 % NF);
    int b = (int)(t2 / NF);
    out[idx] = x[((size_t)(b * TT + f + 2) * HH + (yrow + CRP)) * WW + (xcol + CRP)];
}

extern "C" void kernel_launch(void* const* d_in, const int* in_sizes, int n_in,
                              void* d_out, int out_size, void* d_ws, size_t ws_size,
                              hipStream_t stream) {
    const float* x = (const float*)d_in[0];
    float* out = (float*)d_out;

    // target copy: 12,795,104 elements
    {
        int threads = 256;
        int blocks = (int)((TGT_SIZE + threads - 1) / threads);
        target_copy_kernel<<<blocks, threads, 0, stream>>>(x, out);
    }
    // motion + pred: 4*14*4096 waves = 229,376 waves, 4 waves per 256-thread block
    {
        int threads = 256;
        int total_threads = NV * NF * 64 * 64 * 64;  // waves * 64
        int blocks = total_threads / threads;        // 57,344
        motion_pred_kernel<<<blocks, threads, 0, stream>>>(x, out);
    }
}

// Round 2
// 410.957 us; speedup vs baseline: 2.1931x; 2.1931x over previous
//
#include <hip/hip_runtime.h>

#define HH 512
#define WW 512
#define TT 16
#define NF 14   // pred/target frames per video
#define NV 4    // videos
#define CRP 17
#define CW 478  // cropped width
#define TGT_SIZE ((size_t)NV * NF * CW * CW)

// sum across the 8-lane group (lanes 8g..8g+7)
__device__ __forceinline__ double group8_sum(double v) {
    v += __shfl_xor(v, 1, 64);
    v += __shfl_xor(v, 2, 64);
    v += __shfl_xor(v, 4, 64);
    return v;
}

// Wave-cooperative SAD for one candidate of each of the wave's 8 blocks.
// Lane = row r of block g; pr[] = that row's 8 pixels of the current block.
// Exact f64 sum of f32 abs-diffs (order: serial-8 then 3-stage tree).
__device__ __forceinline__ double cost8(const float* __restrict__ imgI,
                                        const float* pr, int i, int jg,
                                        int y, int x, int r) {
    bool valid = (y >= 0) & (y <= HH - 8) & (x >= 0) & (x <= WW - 8)
               & (y - i <= 8) & (i - y <= 8) & (x - jg <= 8) & (jg - x <= 8);
    int yc = min(max(y, 0), HH - 8);
    int xc = min(max(x, 0), WW - 8);
    const float* row = imgI + (yc + r) * WW + xc;
    double s = 0.0;
    #pragma unroll
    for (int c = 0; c < 8; ++c)
        s += (double)fabsf(pr[c] - row[c]);
    s = group8_sum(s);
    return valid ? s : 1e30;  // LARGE sentinel, uniform per group
}

__global__ void __launch_bounds__(256)
motion_pred_kernel(const float* __restrict__ x, float* __restrict__ out) {
    int gtid = blockIdx.x * 256 + threadIdx.x;
    int wave = gtid >> 6;
    int lane = threadIdx.x & 63;
    int g = lane >> 3;        // block within wave (0..7)
    int r = lane & 7;         // row within block

    int bj0 = (wave & 7) * 8;      // first block col of this wave
    int bi  = (wave >> 3) & 63;    // block row
    int bf  = wave >> 9;           // 0 .. NV*NF-1
    int f   = bf % NF;
    int b   = bf / NF;

    const float* imgP = x + (size_t)(b * TT + f + 1) * HH * WW;  // current
    const float* imgI = x + (size_t)(b * TT + f)     * HH * WW;  // reference

    int i  = bi * 8;
    int jg = (bj0 + g) * 8;

    // load this lane's block row (32B-aligned → two float4)
    float pr[8];
    {
        const float4* prow = (const float4*)(imgP + (size_t)(i + r) * WW + jg);
        float4 p0 = prow[0], p1 = prow[1];
        pr[0] = p0.x; pr[1] = p0.y; pr[2] = p0.z; pr[3] = p0.w;
        pr[4] = p1.x; pr[5] = p1.y; pr[6] = p1.z; pr[7] = p1.w;
    }

    // (dx, dy) tables; reference d[0]=dx, d[1]=dy
    const int LDx[9] = {0,-1, 1,-2, 0, 2,-1, 1, 0};
    const int LDy[9] = {-2,-1,-1, 0, 0, 0, 1, 1, 2};
    const int SDx[5] = {0,-1, 0, 1, 0};
    const int SDy[5] = {-1, 0, 0, 0, 1};

    int y = i, xx = jg;
    double cc = cost8(imgI, pr, i, jg, y, xx, r);  // center cost (carried)
    bool done = (cc == 0.0);
    int k = 0;

    while (__any((!done) && (k < 16))) {
        bool active = (!done) && (k < 16);
        double best = 1e300;
        int bidx = 0;
        #pragma unroll
        for (int q = 0; q < 9; ++q) {
            double cq = (q == 4) ? cc
                                 : cost8(imgI, pr, i, jg, y + LDy[q], xx + LDx[q], r);
            bool lt = cq < best;            // strict '<' => first-min (jnp.argmin)
            best = lt ? cq : best;
            bidx = lt ? q : bidx;
        }
        if (active) {
            y  += LDy[bidx];
            xx += LDx[bidx];
            cc  = best;                      // cost at new center
            done = (bidx == 4);
            k++;
        }
    }

    // SDSP refinement; q=2 is the center → reuse carried cc
    {
        double best = 1e300;
        int bidx = 0;
        #pragma unroll
        for (int q = 0; q < 5; ++q) {
            double cq = (q == 2) ? cc
                                 : cost8(imgI, pr, i, jg, y + SDy[q], xx + SDx[q], r);
            bool lt = cq < best;
            best = lt ? cq : best;
            bidx = lt ? q : bidx;
        }
        y  += SDy[bidx];
        xx += SDx[bidx];
    }

    int dy = y - i, dx = xx - jg;   // |dy|,|dx| <= 8 (invalid moves never win)

    // write this lane's warped row (pred), cropped
    int gy = i + r;
    if (gy >= CRP && gy < HH - CRP) {
        const float* src = imgP + (size_t)(i + dy + r) * WW + (jg + dx);
        size_t obase = TGT_SIZE
            + (((size_t)(b * NF + f)) * CW + (size_t)(gy - CRP)) * CW - CRP;
        #pragma unroll
        for (int c = 0; c < 8; ++c) {
            int gx = jg + c;
            if (gx >= CRP && gx < WW - CRP)
                out[obase + gx] = src[c];
        }
    }
}

__global__ void __launch_bounds__(256)
target_copy_kernel(const float* __restrict__ x, float* __restrict__ out) {
    int col = blockIdx.x * 256 + threadIdx.x;   // 0..511
    if (col >= CW) return;
    int row = blockIdx.y;                        // 0..477
    int bf  = blockIdx.z;                        // 0..55
    int f = bf % NF, b = bf / NF;
    size_t o = (((size_t)bf) * CW + (size_t)row) * CW + (size_t)col;
    out[o] = x[((size_t)(b * TT + f + 2) * HH + (row + CRP)) * WW + (col + CRP)];
}

extern "C" void kernel_launch(void* const* d_in, const int* in_sizes, int n_in,
                              void* d_out, int out_size, void* d_ws, size_t ws_size,
                              hipStream_t stream) {
    const float* x = (const float*)d_in[0];
    float* out = (float*)d_out;

    // target copy: 56 frames × 478 rows × 478 cols
    {
        dim3 grid(2, CW, NV * NF);
        target_copy_kernel<<<grid, 256, 0, stream>>>(x, out);
    }
    // motion + pred: 229,376 blocks, 8 blocks/wave → 28,672 waves → 7168 CTAs
    {
        int waves = NV * NF * 64 * 64 / 8;
        int blocks = waves * 64 / 256;
        motion_pred_kernel<<<blocks, 256, 0, stream>>>(x, out);
    }
}

// Round 3
// 287.602 us; speedup vs baseline: 3.1338x; 1.4289x over previous
//
#include <hip/hip_runtime.h>

#define HH 512
#define WW 512
#define TT 16
#define NF 14   // pred/target frames per video
#define NV 4    // videos
#define CRP 17
#define CW 478  // cropped width
#define TGT_SIZE ((size_t)NV * NF * CW * CW)

#define WROWS 48       // window rows per CTA (4 block-rows: 32 + 2*8 halo)
#define WCOLS 80       // window cols per CTA (8 block-cols: 64 + 2*8 halo)
#define WSTR  84       // padded LDS stride (floats)

// sum across the 8-lane group (lanes 8g..8g+7)
__device__ __forceinline__ double group8_sum(double v) {
    v += __shfl_xor(v, 1, 64);
    v += __shfl_xor(v, 2, 64);
    v += __shfl_xor(v, 4, 64);
    return v;
}

// Wave-cooperative SAD for one candidate of each of the wave's 8 blocks.
// Lane = row r of block g; pr[] = that row's 8 pixels of the current block.
// Reference pixels come from the LDS-staged window. Exact f64 sum
// (pairwise tree per row, then 3-stage cross-lane tree).
__device__ __forceinline__ double cost8(const float* __restrict__ win,
                                        const float* pr, int i, int jg,
                                        int y, int x, int r,
                                        int wy0, int wx0) {
    bool valid = (y >= 0) & (y <= HH - 8) & (x >= 0) & (x <= WW - 8)
               & (y - i <= 8) & (i - y <= 8) & (x - jg <= 8) & (jg - x <= 8);
    int yc = min(max(y, 0), HH - 8);
    int xc = min(max(x, 0), WW - 8);
    const float* row = win + (yc - wy0 + r) * WSTR + (xc - wx0);
    double d0 = (double)fabsf(pr[0] - row[0]) + (double)fabsf(pr[1] - row[1]);
    double d1 = (double)fabsf(pr[2] - row[2]) + (double)fabsf(pr[3] - row[3]);
    double d2 = (double)fabsf(pr[4] - row[4]) + (double)fabsf(pr[5] - row[5]);
    double d3 = (double)fabsf(pr[6] - row[6]) + (double)fabsf(pr[7] - row[7]);
    double s = (d0 + d1) + (d2 + d3);
    s = group8_sum(s);
    return valid ? s : 1e30;  // LARGE sentinel, uniform per group
}

__global__ void __launch_bounds__(256)
motion_pred_kernel(const float* __restrict__ x, float* __restrict__ out) {
    __shared__ float win[WROWS * WSTR];   // 16,128 B

    int cta = blockIdx.x;
    int jb0 = (cta & 7) * 64;          // first pixel col of this CTA's blocks
    int bi0 = ((cta >> 3) & 15) * 4;   // first block row (4 per CTA)
    int bf  = cta >> 7;                // 0 .. NV*NF-1
    int f   = bf % NF;
    int b   = bf / NF;

    const float* imgP = x + (size_t)(b * TT + f + 1) * HH * WW;  // current
    const float* imgI = x + (size_t)(b * TT + f)     * HH * WW;  // reference

    int wy0 = bi0 * 8 - 8;   // window origin (may be out of image; such cells never read)
    int wx0 = jb0 - 8;

    // ---- stage reference window: 48 rows x 20 float4 = 960 float4s ----
    #pragma unroll
    for (int t = 0; t < 4; ++t) {
        int idx = t * 256 + threadIdx.x;
        if (idx < WROWS * (WCOLS / 4)) {
            int row = idx / (WCOLS / 4);
            int c4  = idx - row * (WCOLS / 4);
            int yy  = wy0 + row;
            int xg  = wx0 + c4 * 4;
            if (yy >= 0 && yy < HH && xg >= 0 && xg <= WW - 4) {
                float4 v = *(const float4*)(imgI + (size_t)yy * WW + xg);
                *(float4*)(win + row * WSTR + c4 * 4) = v;
            }
        }
    }
    __syncthreads();

    int w    = threadIdx.x >> 6;   // wave in CTA → block row bi0+w
    int lane = threadIdx.x & 63;
    int g = lane >> 3;             // block within wave (0..7)
    int r = lane & 7;              // row within block

    int i  = (bi0 + w) * 8;
    int jg = jb0 + g * 8;

    // this lane's current-block row (32B-aligned → two float4)
    float pr[8];
    {
        const float4* prow = (const float4*)(imgP + (size_t)(i + r) * WW + jg);
        float4 p0 = prow[0], p1 = prow[1];
        pr[0] = p0.x; pr[1] = p0.y; pr[2] = p0.z; pr[3] = p0.w;
        pr[4] = p1.x; pr[5] = p1.y; pr[6] = p1.z; pr[7] = p1.w;
    }

    // (dx, dy) tables; reference d[0]=dx, d[1]=dy
    const int LDx[9] = {0,-1, 1,-2, 0, 2,-1, 1, 0};
    const int LDy[9] = {-2,-1,-1, 0, 0, 0, 1, 1, 2};
    const int SDx[5] = {0,-1, 0, 1, 0};
    const int SDy[5] = {-1, 0, 0, 0, 1};

    int y = i, xx = jg;
    double cc = cost8(win, pr, i, jg, y, xx, r, wy0, wx0);  // center cost (carried)
    bool done = (cc == 0.0);
    int k = 0;

    while (__any((!done) && (k < 16))) {
        bool active = (!done) && (k < 16);
        double best = 1e300;
        int bidx = 0;
        #pragma unroll
        for (int q = 0; q < 9; ++q) {
            double cq = (q == 4) ? cc
                                 : cost8(win, pr, i, jg, y + LDy[q], xx + LDx[q], r, wy0, wx0);
            bool lt = cq < best;            // strict '<' => first-min (jnp.argmin)
            best = lt ? cq : best;
            bidx = lt ? q : bidx;
        }
        if (active) {
            y  += LDy[bidx];
            xx += LDx[bidx];
            cc  = best;                      // cost at new center
            done = (bidx == 4);
            k++;
        }
    }

    // SDSP refinement; q=2 is the center → reuse carried cc
    {
        double best = 1e300;
        int bidx = 0;
        #pragma unroll
        for (int q = 0; q < 5; ++q) {
            double cq = (q == 2) ? cc
                                 : cost8(win, pr, i, jg, y + SDy[q], xx + SDx[q], r, wy0, wx0);
            bool lt = cq < best;
            best = lt ? cq : best;
            bidx = lt ? q : bidx;
        }
        y  += SDy[bidx];
        xx += SDx[bidx];
    }

    int dy = y - i, dx = xx - jg;   // |dy|,|dx| <= 8 (invalid moves never win)

    // write this lane's warped row (pred), cropped
    int gy = i + r;
    if (gy >= CRP && gy < HH - CRP) {
        const float* src = imgP + (size_t)(i + dy + r) * WW + (jg + dx);
        size_t obase = TGT_SIZE
            + (((size_t)(b * NF + f)) * CW + (size_t)(gy - CRP)) * CW - CRP;
        #pragma unroll
        for (int c = 0; c < 8; ++c) {
            int gx = jg + c;
            if (gx >= CRP && gx < WW - CRP)
                out[obase + gx] = src[c];
        }
    }
}

__global__ void __launch_bounds__(256)
target_copy_kernel(const float* __restrict__ x, float* __restrict__ out) {
    int col = blockIdx.x * 256 + threadIdx.x;   // 0..511
    if (col >= CW) return;
    int row = blockIdx.y;                        // 0..477
    int bf  = blockIdx.z;                        // 0..55
    int f = bf % NF, b = bf / NF;
    size_t o = (((size_t)bf) * CW + (size_t)row) * CW + (size_t)col;
    out[o] = x[((size_t)(b * TT + f + 2) * HH + (row + CRP)) * WW + (col + CRP)];
}

extern "C" void kernel_launch(void* const* d_in, const int* in_sizes, int n_in,
                              void* d_out, int out_size, void* d_ws, size_t ws_size,
                              hipStream_t stream) {
    const float* x = (const float*)d_in[0];
    float* out = (float*)d_out;

    // target copy: 56 frames × 478 rows × 478 cols
    {
        dim3 grid(2, CW, NV * NF);
        target_copy_kernel<<<grid, 256, 0, stream>>>(x, out);
    }
    // motion + pred: 56 frames × 16 bi-groups × 8 bj-groups = 7168 CTAs
    {
        int blocks = NV * NF * 16 * 8;
        motion_pred_kernel<<<blocks, 256, 0, stream>>>(x, out);
    }
}

// Round 4
// 250.056 us; speedup vs baseline: 3.6043x; 1.1501x over previous
//
#include <hip/hip_runtime.h>

#define HH 512
#define WW 512
#define TT 16
#define NF 14   // pred/target frames per video
#define NV 4    // videos
#define CRP 17
#define CW 478  // cropped width
#define TGT_SIZE ((size_t)NV * NF * CW * CW)   // 12,795,104
#define FRAME ((size_t)HH * WW)

#define WROWS 48
#define WCOLS 80
#define WSTR  84
#define CPY   (WROWS * WSTR)     // floats per parity copy (4032)
#define TH    1e-3f              // hybrid fallback margin (bound on f32 tree err ~7e-5)

__device__ __forceinline__ float bf8_sum(float v) {
    v += __shfl_xor(v, 1, 64);
    v += __shfl_xor(v, 2, 64);
    v += __shfl_xor(v, 4, 64);
    return v;
}
__device__ __forceinline__ double bf8_sumd(double v) {
    v += __shfl_xor(v, 1, 64);
    v += __shfl_xor(v, 2, 64);
    v += __shfl_xor(v, 4, 64);
    return v;
}

// fast f32 SAD of this lane's 8-pixel row vs LDS window at bp (8B-aligned), then
// 3-stage group reduce. Deterministic association order.
__device__ __forceinline__ float sad_f32(const float* bp, const float2* pr2) {
    const float2* w2 = (const float2*)bp;
    float2 a0 = w2[0], a1 = w2[1], a2 = w2[2], a3 = w2[3];
    float t0 = fabsf(pr2[0].x - a0.x) + fabsf(pr2[0].y - a0.y);
    float t1 = fabsf(pr2[1].x - a1.x) + fabsf(pr2[1].y - a1.y);
    float t2 = fabsf(pr2[2].x - a2.x) + fabsf(pr2[2].y - a2.y);
    float t3 = fabsf(pr2[3].x - a3.x) + fabsf(pr2[3].y - a3.y);
    return bf8_sum((t0 + t1) + (t2 + t3));
}

// exact path: f32 diffs (matches reference rounding) summed in f64 (order-error ~1e-16,
// far below the ~1e-5 np margins proven by R1-R3's absmax=0.0)
__device__ __forceinline__ double sad_f64(const float* bp, const float2* pr2) {
    const float2* w2 = (const float2*)bp;
    float2 a0 = w2[0], a1 = w2[1], a2 = w2[2], a3 = w2[3];
    double e0 = (double)fabsf(pr2[0].x - a0.x) + (double)fabsf(pr2[0].y - a0.y);
    double e1 = (double)fabsf(pr2[1].x - a1.x) + (double)fabsf(pr2[1].y - a1.y);
    double e2 = (double)fabsf(pr2[2].x - a2.x) + (double)fabsf(pr2[2].y - a2.y);
    double e3 = (double)fabsf(pr2[3].x - a3.x) + (double)fabsf(pr2[3].y - a3.y);
    return bf8_sumd((e0 + e1) + (e2 + e3));
}

__global__ void __launch_bounds__(256)
motion_pred_kernel(const float* __restrict__ x, float* __restrict__ out) {
    __shared__ float win[2 * CPY];   // even copy + shifted-by-1 copy, 32,256 B

    int cta = blockIdx.x;
    int jb0 = (cta & 7) * 64;          // first pixel col of this CTA's blocks
    int bi0 = ((cta >> 3) & 15) * 4;   // first block row (4 per CTA)
    int bf  = cta >> 7;                // 0 .. NV*NF-1
    int f   = bf % NF;
    int b   = bf / NF;

    const float* imgP = x + (size_t)(b * TT + f + 1) * FRAME;  // current
    const float* imgI = x + (size_t)(b * TT + f)     * FRAME;  // reference

    int wy0 = bi0 * 8 - 8;   // window origin
    int wx0 = jb0 - 8;

    // ---- stage reference window into both parity copies ----
    #pragma unroll
    for (int t = 0; t < 4; ++t) {
        int idx = t * 256 + threadIdx.x;
        if (idx < WROWS * (WCOLS / 4)) {
            int row = idx / (WCOLS / 4);
            int c4  = idx - row * (WCOLS / 4);
            int yy  = wy0 + row;
            int xg  = wx0 + c4 * 4;
            if (yy >= 0 && yy < HH && xg >= 0 && xg <= WW - 4) {
                float4 v = *(const float4*)(imgI + (size_t)yy * WW + xg);
                *(float4*)(win + row * WSTR + c4 * 4) = v;   // even copy (16B aligned)
                const float* vv = &v.x;
                #pragma unroll
                for (int k2 = 0; k2 < 4; ++k2) {
                    int oo = c4 * 4 + k2 - 1;                // odd copy: win1[o]=imgI[wx0+1+o]
                    if (oo >= 0) win[CPY + row * WSTR + oo] = vv[k2];
                }
            }
        }
    }
    __syncthreads();

    int w    = threadIdx.x >> 6;   // wave in CTA → block row bi0+w
    int lane = threadIdx.x & 63;
    int g = lane >> 3;             // block within wave (0..7)
    int r = lane & 7;              // row within block

    int i  = (bi0 + w) * 8;
    int jg = jb0 + g * 8;

    // this lane's current-block row as float2 pairs
    float2 pr2[4];
    {
        const float4* prow = (const float4*)(imgP + (size_t)(i + r) * WW + jg);
        float4 p0 = prow[0], p1 = prow[1];
        pr2[0] = make_float2(p0.x, p0.y); pr2[1] = make_float2(p0.z, p0.w);
        pr2[2] = make_float2(p1.x, p1.y); pr2[3] = make_float2(p1.z, p1.w);
    }

    int y = i, xx = jg;
    const float* A0; const float* A1;
    bool vy[5], vx[5];

    // per-center precompute: parity bases + validity intervals
    auto precomp = [&]() {
        int o = xx - wx0;
        int p = o & 1;
        int rowoff = (y - wy0 + r) * WSTR;
        A0 = win + (p ? CPY : 0) + rowoff + (o - p);        // same-parity (even dx)
        A1 = win + (p ? 0 : CPY) + rowoff + (o - (1 - p));  // flipped parity (odd dx)
        int dyL = y - i, dxL = xx - jg;
        int ylo = max(-8 - dyL, -y), yhi = min(8 - dyL, (HH - 8) - y);
        int xlo = max(-8 - dxL, -xx), xhi = min(8 - dxL, (WW - 8) - xx);
        #pragma unroll
        for (int d = -2; d <= 2; ++d) {
            vy[d + 2] = (d >= ylo) && (d <= yhi);
            vx[d + 2] = (d >= xlo) && (d <= xhi);
        }
    };
    auto evalq = [&](int dy, int dx) -> float {
        const float* bp = ((dx & 1) ? A1 : A0) + (dy * WSTR + dx);
        float s = sad_f32(bp, pr2);
        return (vy[dy + 2] && vx[dx + 2]) ? s : 1e30f;
    };
    auto evalqd = [&](int dy, int dx) -> double {
        const float* bp = ((dx & 1) ? A1 : A0) + (dy * WSTR + dx);
        double s = sad_f64(bp, pr2);
        return (vy[dy + 2] && vx[dx + 2]) ? s : 1e30;
    };

    // LDSP tables (dx,dy), index order = reference candidate order
    const int LDx[9] = {0,-1, 1,-2, 0, 2,-1, 1, 0};
    const int LDy[9] = {-2,-1,-1, 0, 0, 0, 1, 1, 2};

    precomp();
    float cc = sad_f32(A0, pr2);       // center cost (center always valid)
    bool done = (cc == 0.0f);          // f32 sum of non-negatives == 0 iff exact 0
    int k = 0;

    while (__any((!done) && (k < 16))) {
        bool active = (!done) && (k < 16);
        precomp();
        float cf[9];
        float m1 = 1e38f, m2 = 1e38f; int b1 = 0;
        #pragma unroll
        for (int q = 0; q < 9; ++q) {
            float cq = (q == 4) ? cc : evalq(LDy[q], LDx[q]);
            cf[q] = cq;
            bool lt = cq < m1;            // strict '<' => first-min (jnp.argmin)
            m2 = lt ? m1 : fminf(m2, cq);
            m1 = lt ? cq : m1;
            b1 = lt ? q  : b1;
        }
        bool needx = (m2 - m1) < TH;      // group-uniform
        if (__any(active && needx)) {     // rare exact fallback
            double e1 = 1e300; int eb = 0;
            #pragma unroll
            for (int q = 0; q < 9; ++q) {
                double eq = evalqd(LDy[q], LDx[q]);
                bool lt = eq < e1;
                e1 = lt ? eq : e1; eb = lt ? q : eb;
            }
            float mf = cf[0];
            #pragma unroll
            for (int q = 1; q < 9; ++q) mf = (eb == q) ? cf[q] : mf;
            if (needx) { b1 = eb; m1 = mf; }
        }
        if (active) {
            int dy = (b1 == 0) ? -2 : (b1 == 1 || b1 == 2) ? -1
                   : (b1 == 6 || b1 == 7) ? 1 : (b1 == 8) ? 2 : 0;
            int dx = (b1 == 1 || b1 == 6) ? -1 : (b1 == 2 || b1 == 7) ? 1
                   : (b1 == 3) ? -2 : (b1 == 5) ? 2 : 0;
            y += dy; xx += dx;
            cc = m1;
            done = (b1 == 4);
            k++;
        }
    }

    // SDSP refinement (center at q=2, carried cc)
    {
        precomp();
        const int SDx[5] = {0,-1, 0, 1, 0};
        const int SDy[5] = {-1, 0, 0, 0, 1};
        float m1 = 1e38f, m2 = 1e38f; int sb = 0;
        #pragma unroll
        for (int q = 0; q < 5; ++q) {
            float cq = (q == 2) ? cc : evalq(SDy[q], SDx[q]);
            bool lt = cq < m1;
            m2 = lt ? m1 : fminf(m2, cq);
            m1 = lt ? cq : m1;
            sb = lt ? q  : sb;
        }
        bool needx = (m2 - m1) < TH;
        if (__any(needx)) {
            double e1 = 1e300; int eb = 0;
            #pragma unroll
            for (int q = 0; q < 5; ++q) {
                double eq = evalqd(SDy[q], SDx[q]);
                bool lt = eq < e1;
                e1 = lt ? eq : e1; eb = lt ? q : eb;
            }
            if (needx) sb = eb;
        }
        y  += (sb == 0) ? -1 : (sb == 4) ? 1 : 0;
        xx += (sb == 1) ? -1 : (sb == 3) ? 1 : 0;
    }

    int dy = y - i, dx = xx - jg;

    // write this lane's warped row (pred), cropped
    int gy = i + r;
    if (gy >= CRP && gy < HH - CRP) {
        const float* src = imgP + (size_t)(i + dy + r) * WW + (jg + dx);
        size_t obase = TGT_SIZE
            + (((size_t)(b * NF + f)) * CW + (size_t)(gy - CRP)) * CW - CRP;
        #pragma unroll
        for (int c = 0; c < 8; ++c) {
            int gx = jg + c;
            if (gx >= CRP && gx < WW - CRP)
                out[obase + gx] = src[c];
        }
    }
}

__global__ void __launch_bounds__(256)
target_copy_kernel(const float* __restrict__ x, float* __restrict__ out) {
    unsigned idx = blockIdx.x * 256 + threadIdx.x;
    if (idx >= (unsigned)(TGT_SIZE / 4)) return;
    unsigned o = idx * 4;
    unsigned fidx = o / (CW * CW);
    unsigned rem  = o - fidx * (CW * CW);
    unsigned rr   = rem / CW;
    unsigned c0   = rem - rr * CW;
    unsigned b    = fidx / NF, fi = fidx - b * NF;
    const float* src = x + (size_t)(b * TT + fi + 2) * FRAME;
    float4 v;
    float* vp = &v.x;
    #pragma unroll
    for (int t = 0; t < 4; ++t) {
        unsigned cc2 = c0 + t, r2 = rr;
        if (cc2 >= CW) { cc2 -= CW; r2 += 1; }   // never crosses a frame (CW² % 4 == 0)
        vp[t] = src[(r2 + CRP) * WW + cc2 + CRP];
    }
    *(float4*)(out + o) = v;
}

extern "C" void kernel_launch(void* const* d_in, const int* in_sizes, int n_in,
                              void* d_out, int out_size, void* d_ws, size_t ws_size,
                              hipStream_t stream) {
    const float* x = (const float*)d_in[0];
    float* out = (float*)d_out;

    // target copy: 3,198,776 float4s
    {
        int n4 = (int)(TGT_SIZE / 4);
        int blocks = (n4 + 255) / 256;
        target_copy_kernel<<<blocks, 256, 0, stream>>>(x, out);
    }
    // motion + pred: 56 frames × 16 bi-groups × 8 bj-groups = 7168 CTAs
    {
        int blocks = NV * NF * 16 * 8;
        motion_pred_kernel<<<blocks, 256, 0, stream>>>(x, out);
    }
}